// Round 15
// baseline (118.005 us; speedup 1.0000x reference)
//
#include <hip/hip_runtime.h>
#include <hip/hip_bf16.h>
#include <math.h>

// TriangleAttention MI355X round 15 = R14 + zero-logit masking.
// B=1, N=256, IN_DIM=128, H=4, D=32.
// Key identity: masked logit = -1e-9*log2e, and exp2f of that == 1.0f == exp2(0).
// So mask = ZERO the logit: pv = exp2(fma(s4, keep, pbm)) with keep in {0,1}
// (bf16 table keepb[bi][j]) and pbm = pair bias pre-multiplied by keep.
// K-projection weights pre-scaled by (1/sqrt(32))*log2e in k_prep, so no
// per-value scale fma. Softmax inner: unpack+unpack+fma+exp per value.
// k_proj: R14 structure (scrambled direct qk stores, 3 barriers); pb branch
//         applies keep at store time. k_attn: R14 minus mask bit machinery.
// k_out: R14 verbatim.
//
// ws: qkbT short[65536*256] (scrambled), Vtb short[4*256*32*256] (phi),
//     wT short[528*128] (K cols pre-scaled), woT short[128*128],
//     keepb short[2*256], pbm short[4*65536] (bf16, *log2e, masked),
//     gate_b short[65536*128] ([p][c]), aob short[4*65536*32]

#define NPOS 65536
#define LN_EPS 1e-5f
#define SCALE_L2E 0.25503487f        // (1/sqrt(32)) * log2(e)

typedef __attribute__((ext_vector_type(8))) short bf16x8;
typedef __attribute__((ext_vector_type(4))) float f32x4;

__device__ __forceinline__ short f2b(float f) {
    union { float f; unsigned u; } c; c.f = f;
    unsigned r = c.u + 0x7FFFu + ((c.u >> 16) & 1u);
    return (short)(r >> 16);
}
__device__ __forceinline__ unsigned cvt_pk(float lo, float hi) {
    unsigned r;
    asm("v_cvt_pk_bf16_f32 %0, %1, %2" : "=v"(r) : "v"(lo), "v"(hi));
    return r;
}
__device__ __forceinline__ float b2f_lo(unsigned u) {
    union { unsigned u; float f; } c; c.u = u << 16; return c.f;
}
__device__ __forceinline__ float b2f_hi(unsigned u) {
    union { unsigned u; float f; } c; c.u = u & 0xFFFF0000u; return c.f;
}

// ------------------------------------------------------------- weight prep
__global__ void k_prep(const float* __restrict__ wq, const float* __restrict__ wg,
                       const float* __restrict__ wp, const float* __restrict__ wo,
                       const int* __restrict__ smask,
                       short* __restrict__ wT, short* __restrict__ woT,
                       short* __restrict__ keepb)
{
    const int idx = blockIdx.x * 256 + threadIdx.x;
    const int stride = gridDim.x * 256;
    for (int i = idx; i < 528 * 128; i += stride) {
        const int o = i >> 7, c = i & 127;
        float v;
        if (o < 128)      v = wq[c * 384 + o];
        else if (o < 256) v = wq[c * 384 + o] * SCALE_L2E;           // K pre-scaled
        else if (o < 384) v = wq[c * 384 + o];
        else if (o < 512) v = wg[c * 128 + (o - 384)];
        else if (o < 516) v = wp[c * 4 + (o - 512)] * 1.4426950408889634f;
        else              v = 0.f;
        wT[i] = f2b(v);
    }
    for (int i = idx; i < 128 * 128; i += stride) {
        const int o = i >> 7, c = i & 127;
        woT[i] = f2b(wo[c * 128 + o]);
    }
    if (blockIdx.x == 0) {
        for (int i = threadIdx.x; i < 512; i += 256) {
            const int bi = i >> 8, j = i & 255;
            const int bj = (smask[j] == 0) ? 1 : 0;
            keepb[i] = (bi == bj) ? (short)0x3F80 : (short)0;   // 1.0 / 0.0 bf16
        }
    }
}

// ------------------------------------------------------------- LN + projections
// 64 positions per block. qk stored direct-to-global (scrambled); 3 barriers.
__global__ __launch_bounds__(256, 4) void k_proj(
    const float* __restrict__ z, const float* __restrict__ ln_g,
    const float* __restrict__ ln_b, const short* __restrict__ wT,
    const float* __restrict__ b_gate, const int* __restrict__ smask,
    short* __restrict__ qkbT, short* __restrict__ Vtb,
    short* __restrict__ pbm, short* __restrict__ gate_b)
{
    __shared__ short sBuf[17920];   // sV [128][72] = 9216 | sZn/sG [64][136] = 8704
    const int t = threadIdx.x, w = t >> 6, l = t & 63;
    const int lg = l & 15, gr = l >> 4;
    const int p0 = blockIdx.x * 64;
    const f32x4 zero4 = {0.f, 0.f, 0.f, 0.f};
    short* sV = sBuf;            // [128][72]
    short* sZn = sBuf + 9216;    // [64][136]  (zn, later reused as gate stage)

    // --- LayerNorm: 4 threads per row, 32 channels each -> sZn [64][136]
    {
        const int row = t >> 2, q = t & 3;
        const float* zr = z + (size_t)(p0 + row) * 128 + q * 32;
        float v[32];
        float s = 0.f, sq = 0.f;
#pragma unroll
        for (int u = 0; u < 8; ++u) {
            const float4 f = ((const float4*)zr)[u];
            v[u * 4 + 0] = f.x; v[u * 4 + 1] = f.y;
            v[u * 4 + 2] = f.z; v[u * 4 + 3] = f.w;
            s += f.x + f.y + f.z + f.w;
            sq += f.x * f.x + f.y * f.y + f.z * f.z + f.w * f.w;
        }
        s  += __shfl_xor(s, 1, 4);  s  += __shfl_xor(s, 2, 4);
        sq += __shfl_xor(sq, 1, 4); sq += __shfl_xor(sq, 2, 4);
        const float mu = s * (1.f / 128.f);
        const float rstd = rsqrtf(sq * (1.f / 128.f) - mu * mu + LN_EPS);
        short tmp[32];
#pragma unroll
        for (int u = 0; u < 32; ++u) {
            const int c = q * 32 + u;
            tmp[u] = f2b((v[u] - mu) * rstd * ln_g[c] + ln_b[c]);
        }
        uint4* dst = (uint4*)(sZn + row * 136 + q * 32);
#pragma unroll
        for (int u = 0; u < 4; ++u) dst[u] = *(uint4*)&tmp[u * 8];
    }
    __syncthreads();   // barrier 1

    bf16x8 a[4][4];
#pragma unroll
    for (int mt = 0; mt < 4; ++mt)
#pragma unroll
        for (int kc = 0; kc < 4; ++kc)
            a[mt][kc] = *(const bf16x8*)(sZn + (mt * 16 + lg) * 136 + kc * 32 + gr * 8);
    __syncthreads();   // barrier 2 (zn region free for gate stage)

    // --- pass A: qk tiles nt 0..15 (SWAPPED), direct scrambled global stores
    short* qblk = qkbT + (size_t)blockIdx.x * 16384;
    for (int nt = w; nt < 16; nt += 4) {
        bf16x8 bfr[4];
#pragma unroll
        for (int kc = 0; kc < 4; ++kc)
            bfr[kc] = *(const bf16x8*)(wT + (size_t)(nt * 16 + lg) * 128 + kc * 32 + gr * 8);
#pragma unroll
        for (int mt = 0; mt < 4; ++mt) {
            f32x4 acc = zero4;
#pragma unroll
            for (int kc = 0; kc < 4; ++kc)
                acc = __builtin_amdgcn_mfma_f32_16x16x32_bf16(bfr[kc], a[mt][kc], acc, 0, 0, 0);
            uint2 pk;
            pk.x = cvt_pk(acc[0], acc[1]);
            pk.y = cvt_pk(acc[2], acc[3]);
            *(uint2*)(qblk + (nt * 4 + mt) * 256 + gr * 64 + lg * 4) = pk;
        }
    }

    // --- pass B: V (staged phi into sV), gate (staged into sZn region), pb direct
    const int mi = (smask[p0 >> 8] == 0) ? 1 : 0;   // query-row mask bit for this block
    for (int nt = 16 + w; nt < 33; nt += 4) {
        bf16x8 bfr[4];
#pragma unroll
        for (int kc = 0; kc < 4; ++kc)
            bfr[kc] = *(const bf16x8*)(wT + (size_t)(nt * 16 + lg) * 128 + kc * 32 + gr * 8);
        const int o = nt * 16 + lg;
#pragma unroll
        for (int mt = 0; mt < 4; ++mt) {
            f32x4 acc = zero4;
#pragma unroll
            for (int kc = 0; kc < 4; ++kc)
                acc = __builtin_amdgcn_mfma_f32_16x16x32_bf16(a[mt][kc], bfr[kc], acc, 0, 0, 0);
            const int pr = p0 + mt * 16 + gr * 4;
            if (o < 384) {
                const int row = o - 256;                    // hh*32 + d
                const int jl = mt * 16 + gr * 4;            // local j, 4-aligned
                const int jp = (jl & 0x23) | ((jl & 12) << 1) | ((jl >> 2) & 4);
                union { unsigned long long u; short sh[4]; } pk;
#pragma unroll
                for (int reg = 0; reg < 4; ++reg) pk.sh[reg] = f2b(acc[reg]);
                *(unsigned long long*)(sV + row * 72 + jp) = pk.u;
            } else if (o < 512) {
                const int c = o - 384;
                const float bg = b_gate[c];
#pragma unroll
                for (int reg = 0; reg < 4; ++reg)
                    sZn[(mt * 16 + gr * 4 + reg) * 136 + c] =
                        f2b(1.f / (1.f + __expf(-(acc[reg] + bg))));
            } else if (o < 516) {
                union { unsigned long long u; short sh[4]; } pk;
#pragma unroll
                for (int reg = 0; reg < 4; ++reg) {
                    const int mj = (smask[(pr + reg) & 255] == 0) ? 1 : 0;
                    pk.sh[reg] = (mi == mj) ? f2b(acc[reg]) : (short)0;  // keep-masked
                }
                *(unsigned long long*)(pbm + (size_t)(o - 512) * NPOS + pr) = pk.u;
            }
        }
    }
    __syncthreads();   // barrier 3

    // --- coalesced write-out: V rows 64B/thread; gate rows 64B/thread
    {
        const int r = p0 >> 8, jbase = p0 & 255;
        const int row = t >> 1, half = t & 1;               // V: 128 rows x 2
        const short* src = sV + row * 72 + half * 32;
        const int hh = row >> 5, d = row & 31;
        short* dst = Vtb + (((size_t)hh * 256 + r) * 32 + d) * 256 + jbase + half * 32;
#pragma unroll
        for (int u = 0; u < 4; ++u)
            *(uint4*)(dst + u * 8) = *(const uint4*)(src + u * 8);

        const int grow = t >> 2, q = t & 3;                 // gate: 64 rows x 4
        const short* gsrc = sZn + grow * 136 + q * 32;
        short* gdst = gate_b + (size_t)(p0 + grow) * 128 + q * 32;
#pragma unroll
        for (int u = 0; u < 4; ++u)
            *(uint4*)(gdst + u * 8) = *(const uint4*)(gsrc + u * 8);
    }
}

// ------------------------------------------------------------- attention
// block = (r, h): grid 1024, XCD-local decode; 4 waves x 64 i.
// Softmax: pv = exp2(fma(s4, keep, pbm)) — zero-logit masking, no bit tests.
__global__ __launch_bounds__(256, 4) void k_attn(
    const short* __restrict__ qkbT, const short* __restrict__ Vtb,
    const short* __restrict__ pbm, const int* __restrict__ smask,
    const short* __restrict__ gate_b, const short* __restrict__ keepb,
    short* __restrict__ aob)
{
    __shared__ short sK[8192];   // [nt][gr][lg][8]  16KB, frag-packed
    __shared__ short sV[8192];   // [kcgr][d^(kcgr&7)][8]  16KB, XOR-swizzled
    const int t = threadIdx.x, wv = t >> 6, l = t & 63;
    const int lg = l & 15, gr = l >> 4;
    const int bid = blockIdx.x;
    const int r = (bid & 7) * 32 + (bid >> 5);   // XCD-local
    const int h = (bid >> 3) & 3;
    const int rb = r * 256;
    const f32x4 zero4 = {0.f, 0.f, 0.f, 0.f};
    bf16x8 ones;
#pragma unroll
    for (int u = 0; u < 8; ++u) ones[u] = (short)0x3F80;

    // ---- stage K_h from scrambled qkbT
#pragma unroll
    for (int it = 0; it < 4; ++it) {
        const int chunk = it * 256 + t;
        const int j = chunk >> 2, dg = chunk & 3;
        const short* kb = qkbT + ((size_t)(r * 4 + (j >> 6))) * 16384
                        + ((8 + h * 2 + (dg >> 1)) * 4 + ((j >> 4) & 3)) * 256
                        + ((dg & 1) * 2) * 64 + (j & 15) * 4;
        uint4 v;
        { const uint2 lo = *(const uint2*)kb, hi = *(const uint2*)(kb + 64);
          v.x = lo.x; v.y = lo.y; v.z = hi.x; v.w = hi.y; }
        *(uint4*)(sK + (((j >> 4) * 4 + dg) * 16 + (j & 15)) * 8) = v;
    }
    // ---- stage V_h: contiguous 4KB per iteration (phi layout in Vtb)
#pragma unroll
    for (int it = 0; it < 4; ++it) {
        const int d = it * 8 + (t >> 5), kcgr = t & 31;
        const uint4 v = *(const uint4*)(Vtb + (((size_t)h * 256 + r) * 32 + d) * 256 + kcgr * 8);
        *(uint4*)(sV + (kcgr * 32 + (d ^ (kcgr & 7))) * 8) = v;
    }
    __syncthreads();

    for (int tl = 0; tl < 4; ++tl) {
        const int i0 = wv * 64 + tl * 16;
        // Q frag from scrambled qkbT
        bf16x8 qf;
        {
            const short* qb = qkbT + ((size_t)(r * 4 + wv)) * 16384
                            + ((h * 2 + (gr >> 1)) * 4 + tl) * 256
                            + ((gr & 1) * 2) * 64 + lg * 4;
            union { bf16x8 v; uint2 u2[2]; } qu;
            qu.u2[0] = *(const uint2*)qb;
            qu.u2[1] = *(const uint2*)(qb + 64);
            qf = qu.v;
        }
        const int bi = (smask[i0 + lg] == 0) ? 1 : 0;
        const short* kprow = keepb + bi * 256;
        const short* pbrow = pbm + (size_t)h * NPOS + (size_t)(i0 + lg) * 256;

        f32x4 o0 = zero4, o1 = zero4, o2 = zero4;

        // ---- half A: softmax nt 0..7 -> pkA, then PV kc 0..3
        unsigned pkA[16];
#pragma unroll
        for (int nt = 0; nt < 8; ++nt) {
            const bf16x8 kf = *(const bf16x8*)(sK + ((nt * 4 + gr) * 16 + lg) * 8);
            const uint2 pbp = *(const uint2*)(pbrow + nt * 16 + gr * 4);
            const uint2 kpp = *(const uint2*)(kprow + nt * 16 + gr * 4);
            const f32x4 s4 = __builtin_amdgcn_mfma_f32_16x16x32_bf16(kf, qf, zero4, 0, 0, 0);
            const float pbv[4] = { b2f_lo(pbp.x), b2f_hi(pbp.x), b2f_lo(pbp.y), b2f_hi(pbp.y) };
            const float kpv[4] = { b2f_lo(kpp.x), b2f_hi(kpp.x), b2f_lo(kpp.y), b2f_hi(kpp.y) };
            float pv[4];
#pragma unroll
            for (int reg = 0; reg < 4; ++reg)
                pv[reg] = exp2f(fmaf(s4[reg], kpv[reg], pbv[reg]));
            pkA[nt * 2 + 0] = cvt_pk(pv[0], pv[1]);
            pkA[nt * 2 + 1] = cvt_pk(pv[2], pv[3]);
        }
        __builtin_amdgcn_s_setprio(1);
#pragma unroll
        for (int kc = 0; kc < 4; ++kc) {
            const int kcgr = kc * 4 + gr, c7 = kcgr & 7;
            const bf16x8 pa = *(const bf16x8*)(&pkA[kc * 4]);
            const bf16x8 v0 = *(const bf16x8*)(sV + (kcgr * 32 + (lg ^ c7)) * 8);
            const bf16x8 v1 = *(const bf16x8*)(sV + (kcgr * 32 + 16 + (lg ^ c7)) * 8);
            o0 = __builtin_amdgcn_mfma_f32_16x16x32_bf16(pa, v0, o0, 0, 0, 0);
            o1 = __builtin_amdgcn_mfma_f32_16x16x32_bf16(pa, v1, o1, 0, 0, 0);
            o2 = __builtin_amdgcn_mfma_f32_16x16x32_bf16(pa, ones, o2, 0, 0, 0);
        }
        __builtin_amdgcn_s_setprio(0);

        // ---- half B: softmax nt 8..15, then PV kc 4..7
        unsigned pkB[16];
#pragma unroll
        for (int nt = 8; nt < 16; ++nt) {
            const bf16x8 kf = *(const bf16x8*)(sK + ((nt * 4 + gr) * 16 + lg) * 8);
            const uint2 pbp = *(const uint2*)(pbrow + nt * 16 + gr * 4);
            const uint2 kpp = *(const uint2*)(kprow + nt * 16 + gr * 4);
            const f32x4 s4 = __builtin_amdgcn_mfma_f32_16x16x32_bf16(kf, qf, zero4, 0, 0, 0);
            const float pbv[4] = { b2f_lo(pbp.x), b2f_hi(pbp.x), b2f_lo(pbp.y), b2f_hi(pbp.y) };
            const float kpv[4] = { b2f_lo(kpp.x), b2f_hi(kpp.x), b2f_lo(kpp.y), b2f_hi(kpp.y) };
            float pv[4];
#pragma unroll
            for (int reg = 0; reg < 4; ++reg)
                pv[reg] = exp2f(fmaf(s4[reg], kpv[reg], pbv[reg]));
            pkB[(nt - 8) * 2 + 0] = cvt_pk(pv[0], pv[1]);
            pkB[(nt - 8) * 2 + 1] = cvt_pk(pv[2], pv[3]);
        }
        __builtin_amdgcn_s_setprio(1);
#pragma unroll
        for (int kc = 4; kc < 8; ++kc) {
            const int kcgr = kc * 4 + gr, c7 = kcgr & 7;
            const bf16x8 pa = *(const bf16x8*)(&pkB[(kc - 4) * 4]);
            const bf16x8 v0 = *(const bf16x8*)(sV + (kcgr * 32 + (lg ^ c7)) * 8);
            const bf16x8 v1 = *(const bf16x8*)(sV + (kcgr * 32 + 16 + (lg ^ c7)) * 8);
            o0 = __builtin_amdgcn_mfma_f32_16x16x32_bf16(pa, v0, o0, 0, 0, 0);
            o1 = __builtin_amdgcn_mfma_f32_16x16x32_bf16(pa, v1, o1, 0, 0, 0);
            o2 = __builtin_amdgcn_mfma_f32_16x16x32_bf16(pa, ones, o2, 0, 0, 0);
        }
        __builtin_amdgcn_s_setprio(0);

        // ---- epilogue: normalize, gate, write aob[h][p][d] (bf16)
#pragma unroll
        for (int reg = 0; reg < 4; ++reg) {
            const int p = rb + i0 + gr * 4 + reg;
            const float g0 = b2f_lo((unsigned)*(const unsigned short*)(gate_b + (size_t)p * 128 + h * 32 + lg));
            const float g1 = b2f_lo((unsigned)*(const unsigned short*)(gate_b + (size_t)p * 128 + h * 32 + 16 + lg));
            const float inv = 1.f / o2[reg];
            short* dst = aob + ((size_t)h * NPOS + p) * 32;
            dst[lg]      = f2b(o0[reg] * inv * g0);
            dst[16 + lg] = f2b(o1[reg] * inv * g1);
        }
    }
}

// ------------------------------------------------------------- out projection
__global__ __launch_bounds__(256) void k_out(
    const short* __restrict__ aob, const short* __restrict__ woT,
    const float* __restrict__ b_out, float* __restrict__ out)
{
    const int t = threadIdx.x, w = t >> 6, l = t & 63;
    const int lg = l & 15, gr = l >> 4;
    const int p0 = blockIdx.x * 64;
    const f32x4 zero4 = {0.f, 0.f, 0.f, 0.f};

    bf16x8 a[4][4];   // [mt][kc]; kc = head
#pragma unroll
    for (int mt = 0; mt < 4; ++mt)
#pragma unroll
        for (int kc = 0; kc < 4; ++kc)
            a[mt][kc] = *(const bf16x8*)(aob + ((size_t)kc * NPOS + p0 + mt * 16 + lg) * 32 + gr * 8);

    for (int nt = w; nt < 8; nt += 4) {
        bf16x8 bw[4];
#pragma unroll
        for (int kc = 0; kc < 4; ++kc)
            bw[kc] = *(const bf16x8*)(woT + (size_t)(nt * 16 + lg) * 128 + kc * 32 + gr * 8);
        const int o = nt * 16 + lg;
        const float bo = b_out[o];
#pragma unroll
        for (int mt = 0; mt < 4; ++mt) {
            f32x4 c = zero4;
#pragma unroll
            for (int kc = 0; kc < 4; ++kc)
                c = __builtin_amdgcn_mfma_f32_16x16x32_bf16(a[mt][kc], bw[kc], c, 0, 0, 0);
#pragma unroll
            for (int reg = 0; reg < 4; ++reg)
                out[(size_t)(p0 + mt * 16 + gr * 4 + reg) * 128 + o] = c[reg] + bo;
        }
    }
}

// ------------------------------------------------------------- launch
extern "C" void kernel_launch(void* const* d_in, const int* in_sizes, int n_in,
                              void* d_out, int out_size, void* d_ws, size_t ws_size,
                              hipStream_t stream)
{
    const float* z      = (const float*)d_in[0];
    const int*   smask  = (const int*)d_in[1];
    const float* ln_g   = (const float*)d_in[2];
    const float* ln_b   = (const float*)d_in[3];
    const float* w_qkv  = (const float*)d_in[4];
    const float* w_pair = (const float*)d_in[5];
    const float* w_gate = (const float*)d_in[6];
    const float* b_gate = (const float*)d_in[7];
    const float* w_out  = (const float*)d_in[8];
    const float* b_out  = (const float*)d_in[9];
    float* out = (float*)d_out;

    short* ws      = (short*)d_ws;
    short* qkbT    = ws;                                   // 65536*256 (scrambled)
    short* Vtb     = qkbT + (size_t)NPOS * 256;            // 8388608 (phi)
    short* wT      = Vtb + (size_t)8388608;                // 528*128
    short* woT     = wT + 528 * 128;                       // 128*128
    short* keepb   = woT + 128 * 128;                      // 2*256
    short* pbm     = keepb + 512;                          // 4*65536 (masked)
    short* gate_b  = pbm + (size_t)4 * NPOS;               // 65536*128 ([p][c])
    short* aob     = gate_b + (size_t)NPOS * 128;          // 4*65536*32

    k_prep<<<64, 256, 0, stream>>>(w_qkv, w_gate, w_pair, w_out, smask, wT, woT, keepb);
    k_proj<<<NPOS / 64, 256, 0, stream>>>(z, ln_g, ln_b, wT, b_gate, smask, qkbT, Vtb, pbm, gate_b);
    k_attn<<<1024, 256, 0, stream>>>(qkbT, Vtb, pbm, smask, gate_b, keepb, aob);
    k_out<<<NPOS / 64, 256, 0, stream>>>(aob, woT, b_out, out);
}

// Round 16
// 106.947 us; speedup vs baseline: 1.1034x; 1.1034x over previous
//
#include <hip/hip_runtime.h>
#include <hip/hip_bf16.h>
#include <math.h>

// TriangleAttention MI355X round 16 = R14 + k_attn load-batching.
// B=1, N=256, IN_DIM=128, H=4, D=32.
// k_attn changes vs R14 (only kernel changed):
//   - pbp[16] prefetched in one batch at tile start (latency overlapped)
//   - gate words prefetched at tile start (epilogue-only use)
//   - mask select hoisted: mjc = bi ? ~mjb : mjb once per tile; per value
//     masked = (mjc>>bit)&1 -> cndmask (2 ops vs 4)
// k_prep / k_proj / k_out: R14 verbatim.
//
// ws: qkbT short[65536*256] (scrambled), Vtb short[4*256*32*256] (phi),
//     wT short[528*128], woT short[128*128], mjbg u32[16],
//     pbb short[4*65536], gate_b short[65536*128] ([p][c]), aob short[4*65536*32]

#define NPOS 65536
#define LN_EPS 1e-5f
#define SCALE_L2E 0.25503487f        // (1/sqrt(32)) * log2(e)
#define MASKVAL  -1.4426950e-9f      // -1e-9 * log2(e)

typedef __attribute__((ext_vector_type(8))) short bf16x8;
typedef __attribute__((ext_vector_type(4))) float f32x4;

__device__ __forceinline__ short f2b(float f) {
    union { float f; unsigned u; } c; c.f = f;
    unsigned r = c.u + 0x7FFFu + ((c.u >> 16) & 1u);
    return (short)(r >> 16);
}
__device__ __forceinline__ unsigned cvt_pk(float lo, float hi) {
    unsigned r;
    asm("v_cvt_pk_bf16_f32 %0, %1, %2" : "=v"(r) : "v"(lo), "v"(hi));
    return r;
}
__device__ __forceinline__ float b2f_lo(unsigned u) {
    union { unsigned u; float f; } c; c.u = u << 16; return c.f;
}
__device__ __forceinline__ float b2f_hi(unsigned u) {
    union { unsigned u; float f; } c; c.u = u & 0xFFFF0000u; return c.f;
}

// ------------------------------------------------------------- weight prep
__global__ void k_prep(const float* __restrict__ wq, const float* __restrict__ wg,
                       const float* __restrict__ wp, const float* __restrict__ wo,
                       const int* __restrict__ smask,
                       short* __restrict__ wT, short* __restrict__ woT,
                       unsigned* __restrict__ mjbg)
{
    const int idx = blockIdx.x * 256 + threadIdx.x;
    const int stride = gridDim.x * 256;
    for (int i = idx; i < 528 * 128; i += stride) {
        const int o = i >> 7, c = i & 127;
        float v;
        if (o < 384)      v = wq[c * 384 + o];
        else if (o < 512) v = wg[c * 128 + (o - 384)];
        else if (o < 516) v = wp[c * 4 + (o - 512)] * 1.4426950408889634f;
        else              v = 0.f;
        wT[i] = f2b(v);
    }
    for (int i = idx; i < 128 * 128; i += stride) {
        const int o = i >> 7, c = i & 127;
        woT[i] = f2b(wo[c * 128 + o]);
    }
    if (blockIdx.x == 0 && threadIdx.x < 8) {
        const int gr = threadIdx.x >> 1, hw = threadIdx.x & 1;
        unsigned wbits = 0;
        for (int b = 0; b < 32; ++b) {
            const int k = hw * 32 + b;                    // k = nt*4 + reg
            const int j = (k >> 2) * 16 + gr * 4 + (k & 3);
            if (smask[j] == 0) wbits |= (1u << b);
        }
        mjbg[threadIdx.x] = wbits;
    }
}

// ------------------------------------------------------------- LN + projections
// 64 positions per block. qk stored direct-to-global (scrambled); 3 barriers.
__global__ __launch_bounds__(256, 4) void k_proj(
    const float* __restrict__ z, const float* __restrict__ ln_g,
    const float* __restrict__ ln_b, const short* __restrict__ wT,
    const float* __restrict__ b_gate, short* __restrict__ qkbT,
    short* __restrict__ Vtb, short* __restrict__ pbb, short* __restrict__ gate_b)
{
    __shared__ short sBuf[17920];   // sV [128][72] = 9216 | sZn/sG [64][136] = 8704
    const int t = threadIdx.x, w = t >> 6, l = t & 63;
    const int lg = l & 15, gr = l >> 4;
    const int p0 = blockIdx.x * 64;
    const f32x4 zero4 = {0.f, 0.f, 0.f, 0.f};
    short* sV = sBuf;            // [128][72]
    short* sZn = sBuf + 9216;    // [64][136]  (zn, later reused as gate stage)

    // --- LayerNorm: 4 threads per row, 32 channels each -> sZn [64][136]
    {
        const int row = t >> 2, q = t & 3;
        const float* zr = z + (size_t)(p0 + row) * 128 + q * 32;
        float v[32];
        float s = 0.f, sq = 0.f;
#pragma unroll
        for (int u = 0; u < 8; ++u) {
            const float4 f = ((const float4*)zr)[u];
            v[u * 4 + 0] = f.x; v[u * 4 + 1] = f.y;
            v[u * 4 + 2] = f.z; v[u * 4 + 3] = f.w;
            s += f.x + f.y + f.z + f.w;
            sq += f.x * f.x + f.y * f.y + f.z * f.z + f.w * f.w;
        }
        s  += __shfl_xor(s, 1, 4);  s  += __shfl_xor(s, 2, 4);
        sq += __shfl_xor(sq, 1, 4); sq += __shfl_xor(sq, 2, 4);
        const float mu = s * (1.f / 128.f);
        const float rstd = rsqrtf(sq * (1.f / 128.f) - mu * mu + LN_EPS);
        short tmp[32];
#pragma unroll
        for (int u = 0; u < 32; ++u) {
            const int c = q * 32 + u;
            tmp[u] = f2b((v[u] - mu) * rstd * ln_g[c] + ln_b[c]);
        }
        uint4* dst = (uint4*)(sZn + row * 136 + q * 32);
#pragma unroll
        for (int u = 0; u < 4; ++u) dst[u] = *(uint4*)&tmp[u * 8];
    }
    __syncthreads();   // barrier 1

    bf16x8 a[4][4];
#pragma unroll
    for (int mt = 0; mt < 4; ++mt)
#pragma unroll
        for (int kc = 0; kc < 4; ++kc)
            a[mt][kc] = *(const bf16x8*)(sZn + (mt * 16 + lg) * 136 + kc * 32 + gr * 8);
    __syncthreads();   // barrier 2 (zn region free for gate stage)

    // --- pass A: qk tiles nt 0..15 (SWAPPED), direct scrambled global stores
    short* qblk = qkbT + (size_t)blockIdx.x * 16384;
    for (int nt = w; nt < 16; nt += 4) {
        bf16x8 bfr[4];
#pragma unroll
        for (int kc = 0; kc < 4; ++kc)
            bfr[kc] = *(const bf16x8*)(wT + (size_t)(nt * 16 + lg) * 128 + kc * 32 + gr * 8);
#pragma unroll
        for (int mt = 0; mt < 4; ++mt) {
            f32x4 acc = zero4;
#pragma unroll
            for (int kc = 0; kc < 4; ++kc)
                acc = __builtin_amdgcn_mfma_f32_16x16x32_bf16(bfr[kc], a[mt][kc], acc, 0, 0, 0);
            uint2 pk;
            pk.x = cvt_pk(acc[0], acc[1]);
            pk.y = cvt_pk(acc[2], acc[3]);
            *(uint2*)(qblk + (nt * 4 + mt) * 256 + gr * 64 + lg * 4) = pk;
        }
    }

    // --- pass B: V (staged phi into sV), gate (staged into sZn region), pb direct
    for (int nt = 16 + w; nt < 33; nt += 4) {
        bf16x8 bfr[4];
#pragma unroll
        for (int kc = 0; kc < 4; ++kc)
            bfr[kc] = *(const bf16x8*)(wT + (size_t)(nt * 16 + lg) * 128 + kc * 32 + gr * 8);
        const int o = nt * 16 + lg;
#pragma unroll
        for (int mt = 0; mt < 4; ++mt) {
            f32x4 acc = zero4;
#pragma unroll
            for (int kc = 0; kc < 4; ++kc)
                acc = __builtin_amdgcn_mfma_f32_16x16x32_bf16(a[mt][kc], bfr[kc], acc, 0, 0, 0);
            const int pr = p0 + mt * 16 + gr * 4;
            if (o < 384) {
                const int row = o - 256;                    // hh*32 + d
                const int jl = mt * 16 + gr * 4;            // local j, 4-aligned
                const int jp = (jl & 0x23) | ((jl & 12) << 1) | ((jl >> 2) & 4);
                union { unsigned long long u; short sh[4]; } pk;
#pragma unroll
                for (int reg = 0; reg < 4; ++reg) pk.sh[reg] = f2b(acc[reg]);
                *(unsigned long long*)(sV + row * 72 + jp) = pk.u;
            } else if (o < 512) {
                const int c = o - 384;
                const float bg = b_gate[c];
#pragma unroll
                for (int reg = 0; reg < 4; ++reg)
                    sZn[(mt * 16 + gr * 4 + reg) * 136 + c] =
                        f2b(1.f / (1.f + __expf(-(acc[reg] + bg))));
            } else if (o < 516) {
                union { unsigned long long u; short sh[4]; } pk;
#pragma unroll
                for (int reg = 0; reg < 4; ++reg) pk.sh[reg] = f2b(acc[reg]);
                *(unsigned long long*)(pbb + (size_t)(o - 512) * NPOS + pr) = pk.u;
            }
        }
    }
    __syncthreads();   // barrier 3

    // --- coalesced write-out: V rows 64B/thread; gate rows 64B/thread
    {
        const int r = p0 >> 8, jbase = p0 & 255;
        const int row = t >> 1, half = t & 1;               // V: 128 rows x 2
        const short* src = sV + row * 72 + half * 32;
        const int hh = row >> 5, d = row & 31;
        short* dst = Vtb + (((size_t)hh * 256 + r) * 32 + d) * 256 + jbase + half * 32;
#pragma unroll
        for (int u = 0; u < 4; ++u)
            *(uint4*)(dst + u * 8) = *(const uint4*)(src + u * 8);

        const int grow = t >> 2, q = t & 3;                 // gate: 64 rows x 4
        const short* gsrc = sZn + grow * 136 + q * 32;
        short* gdst = gate_b + (size_t)(p0 + grow) * 128 + q * 32;
#pragma unroll
        for (int u = 0; u < 4; ++u)
            *(uint4*)(gdst + u * 8) = *(const uint4*)(gsrc + u * 8);
    }
}

// ------------------------------------------------------------- attention
// block = (r, h): grid 1024, XCD-local decode; 4 waves x 64 i.
// Tile-start batched loads (qf, pbp[16], gate); hoisted mask word mjc.
__global__ __launch_bounds__(256, 4) void k_attn(
    const short* __restrict__ qkbT, const short* __restrict__ Vtb,
    const short* __restrict__ pbb, const int* __restrict__ smask,
    const short* __restrict__ gate_b, const unsigned* __restrict__ mjbg,
    short* __restrict__ aob)
{
    __shared__ short sK[8192];   // [nt][gr][lg][8]  16KB, frag-packed
    __shared__ short sV[8192];   // [kcgr][d^(kcgr&7)][8]  16KB, XOR-swizzled
    const int t = threadIdx.x, wv = t >> 6, l = t & 63;
    const int lg = l & 15, gr = l >> 4;
    const int bid = blockIdx.x;
    const int r = (bid & 7) * 32 + (bid >> 5);   // XCD-local
    const int h = (bid >> 3) & 3;
    const int rb = r * 256;
    const f32x4 zero4 = {0.f, 0.f, 0.f, 0.f};
    const unsigned long long mjb = ((const unsigned long long*)mjbg)[gr];
    bf16x8 ones;
#pragma unroll
    for (int u = 0; u < 8; ++u) ones[u] = (short)0x3F80;

    // ---- stage K_h from scrambled qkbT
#pragma unroll
    for (int it = 0; it < 4; ++it) {
        const int chunk = it * 256 + t;
        const int j = chunk >> 2, dg = chunk & 3;
        const short* kb = qkbT + ((size_t)(r * 4 + (j >> 6))) * 16384
                        + ((8 + h * 2 + (dg >> 1)) * 4 + ((j >> 4) & 3)) * 256
                        + ((dg & 1) * 2) * 64 + (j & 15) * 4;
        uint4 v;
        { const uint2 lo = *(const uint2*)kb, hi = *(const uint2*)(kb + 64);
          v.x = lo.x; v.y = lo.y; v.z = hi.x; v.w = hi.y; }
        *(uint4*)(sK + (((j >> 4) * 4 + dg) * 16 + (j & 15)) * 8) = v;
    }
    // ---- stage V_h: contiguous 4KB per iteration (phi layout in Vtb)
#pragma unroll
    for (int it = 0; it < 4; ++it) {
        const int d = it * 8 + (t >> 5), kcgr = t & 31;
        const uint4 v = *(const uint4*)(Vtb + (((size_t)h * 256 + r) * 32 + d) * 256 + kcgr * 8);
        *(uint4*)(sV + (kcgr * 32 + (d ^ (kcgr & 7))) * 8) = v;
    }
    __syncthreads();

    for (int tl = 0; tl < 4; ++tl) {
        const int i0 = wv * 64 + tl * 16;
        // ---- batched tile-start loads: qf, pbp[16], gate (all independent)
        bf16x8 qf;
        {
            const short* qb = qkbT + ((size_t)(r * 4 + wv)) * 16384
                            + ((h * 2 + (gr >> 1)) * 4 + tl) * 256
                            + ((gr & 1) * 2) * 64 + lg * 4;
            union { bf16x8 v; uint2 u2[2]; } qu;
            qu.u2[0] = *(const uint2*)qb;
            qu.u2[1] = *(const uint2*)(qb + 64);
            qf = qu.v;
        }
        const short* pbrow = pbb + (size_t)h * NPOS + (size_t)(i0 + lg) * 256;
        uint2 pbp[16];
#pragma unroll
        for (int nt = 0; nt < 16; ++nt)
            pbp[nt] = *(const uint2*)(pbrow + nt * 16 + gr * 4);
        const uint2 gu0 = *(const uint2*)(gate_b + (size_t)(rb + i0 + gr * 4) * 128 + h * 32 + lg);      // scalarized below
        const bool bi = smask[i0 + lg] == 0;
        const unsigned long long mjc = bi ? ~mjb : mjb;   // hoisted mask word

        f32x4 o0 = zero4, o1 = zero4, o2 = zero4;

        // ---- half A: softmax nt 0..7 -> pkA, then PV kc 0..3
        unsigned pkA[16];
#pragma unroll
        for (int nt = 0; nt < 8; ++nt) {
            const bf16x8 kf = *(const bf16x8*)(sK + ((nt * 4 + gr) * 16 + lg) * 8);
            const f32x4 s4 = __builtin_amdgcn_mfma_f32_16x16x32_bf16(kf, qf, zero4, 0, 0, 0);
            const unsigned px = pbp[nt].x, py = pbp[nt].y;
            const float pbv[4] = { b2f_lo(px), b2f_hi(px), b2f_lo(py), b2f_hi(py) };
            float pv[4];
#pragma unroll
            for (int reg = 0; reg < 4; ++reg) {
                float lv = fmaf(s4[reg], SCALE_L2E, pbv[reg]);
                lv = ((mjc >> (nt * 4 + reg)) & 1) ? MASKVAL : lv;
                pv[reg] = exp2f(lv);
            }
            pkA[nt * 2 + 0] = cvt_pk(pv[0], pv[1]);
            pkA[nt * 2 + 1] = cvt_pk(pv[2], pv[3]);
        }
        __builtin_amdgcn_s_setprio(1);
#pragma unroll
        for (int kc = 0; kc < 4; ++kc) {
            const int kcgr = kc * 4 + gr, c7 = kcgr & 7;
            const bf16x8 pa = *(const bf16x8*)(&pkA[kc * 4]);
            const bf16x8 v0 = *(const bf16x8*)(sV + (kcgr * 32 + (lg ^ c7)) * 8);
            const bf16x8 v1 = *(const bf16x8*)(sV + (kcgr * 32 + 16 + (lg ^ c7)) * 8);
            o0 = __builtin_amdgcn_mfma_f32_16x16x32_bf16(pa, v0, o0, 0, 0, 0);
            o1 = __builtin_amdgcn_mfma_f32_16x16x32_bf16(pa, v1, o1, 0, 0, 0);
            o2 = __builtin_amdgcn_mfma_f32_16x16x32_bf16(pa, ones, o2, 0, 0, 0);
        }
        __builtin_amdgcn_s_setprio(0);

        // ---- half B: softmax nt 8..15, then PV kc 4..7
        unsigned pkB[16];
#pragma unroll
        for (int nt = 8; nt < 16; ++nt) {
            const bf16x8 kf = *(const bf16x8*)(sK + ((nt * 4 + gr) * 16 + lg) * 8);
            const f32x4 s4 = __builtin_amdgcn_mfma_f32_16x16x32_bf16(kf, qf, zero4, 0, 0, 0);
            const unsigned px = pbp[nt].x, py = pbp[nt].y;
            const float pbv[4] = { b2f_lo(px), b2f_hi(px), b2f_lo(py), b2f_hi(py) };
            float pv[4];
#pragma unroll
            for (int reg = 0; reg < 4; ++reg) {
                float lv = fmaf(s4[reg], SCALE_L2E, pbv[reg]);
                lv = ((mjc >> (nt * 4 + reg)) & 1) ? MASKVAL : lv;
                pv[reg] = exp2f(lv);
            }
            pkB[(nt - 8) * 2 + 0] = cvt_pk(pv[0], pv[1]);
            pkB[(nt - 8) * 2 + 1] = cvt_pk(pv[2], pv[3]);
        }
        __builtin_amdgcn_s_setprio(1);
#pragma unroll
        for (int kc = 4; kc < 8; ++kc) {
            const int kcgr = kc * 4 + gr, c7 = kcgr & 7;
            const bf16x8 pa = *(const bf16x8*)(&pkB[(kc - 4) * 4]);
            const bf16x8 v0 = *(const bf16x8*)(sV + (kcgr * 32 + (lg ^ c7)) * 8);
            const bf16x8 v1 = *(const bf16x8*)(sV + (kcgr * 32 + 16 + (lg ^ c7)) * 8);
            o0 = __builtin_amdgcn_mfma_f32_16x16x32_bf16(pa, v0, o0, 0, 0, 0);
            o1 = __builtin_amdgcn_mfma_f32_16x16x32_bf16(pa, v1, o1, 0, 0, 0);
            o2 = __builtin_amdgcn_mfma_f32_16x16x32_bf16(pa, ones, o2, 0, 0, 0);
        }
        __builtin_amdgcn_s_setprio(0);

        // ---- epilogue: normalize, gate, write aob[h][p][d] (bf16)
        // gate: need per-reg rows; load the remaining 3+4 words here (overlap ok)
#pragma unroll
        for (int reg = 0; reg < 4; ++reg) {
            const int p = rb + i0 + gr * 4 + reg;
            const unsigned gw0 = (reg == 0) ? gu0.x
                : (unsigned)*(const unsigned short*)(gate_b + (size_t)p * 128 + h * 32 + lg)
                  | ((unsigned)*(const unsigned short*)(gate_b + (size_t)p * 128 + h * 32 + lg) << 16);
            const float g0 = (reg == 0) ? b2f_lo(gu0.x)
                : b2f_lo((unsigned)*(const unsigned short*)(gate_b + (size_t)p * 128 + h * 32 + lg));
            const float g1 = b2f_lo((unsigned)*(const unsigned short*)(gate_b + (size_t)p * 128 + h * 32 + 16 + lg));
            (void)gw0;
            const float inv = 1.f / o2[reg];
            short* dst = aob + ((size_t)h * NPOS + p) * 32;
            dst[lg]      = f2b(o0[reg] * inv * g0);
            dst[16 + lg] = f2b(o1[reg] * inv * g1);
        }
    }
}

// ------------------------------------------------------------- out projection
__global__ __launch_bounds__(256) void k_out(
    const short* __restrict__ aob, const short* __restrict__ woT,
    const float* __restrict__ b_out, float* __restrict__ out)
{
    const int t = threadIdx.x, w = t >> 6, l = t & 63;
    const int lg = l & 15, gr = l >> 4;
    const int p0 = blockIdx.x * 64;
    const f32x4 zero4 = {0.f, 0.f, 0.f, 0.f};

    bf16x8 a[4][4];   // [mt][kc]; kc = head
#pragma unroll
    for (int mt = 0; mt < 4; ++mt)
#pragma unroll
        for (int kc = 0; kc < 4; ++kc)
            a[mt][kc] = *(const bf16x8*)(aob + ((size_t)kc * NPOS + p0 + mt * 16 + lg) * 32 + gr * 8);

    for (int nt = w; nt < 8; nt += 4) {
        bf16x8 bw[4];
#pragma unroll
        for (int kc = 0; kc < 4; ++kc)
            bw[kc] = *(const bf16x8*)(woT + (size_t)(nt * 16 + lg) * 128 + kc * 32 + gr * 8);
        const int o = nt * 16 + lg;
        const float bo = b_out[o];
#pragma unroll
        for (int mt = 0; mt < 4; ++mt) {
            f32x4 c = zero4;
#pragma unroll
            for (int kc = 0; kc < 4; ++kc)
                c = __builtin_amdgcn_mfma_f32_16x16x32_bf16(a[mt][kc], bw[kc], c, 0, 0, 0);
#pragma unroll
            for (int reg = 0; reg < 4; ++reg)
                out[(size_t)(p0 + mt * 16 + gr * 4 + reg) * 128 + o] = c[reg] + bo;
        }
    }
}

// ------------------------------------------------------------- launch
extern "C" void kernel_launch(void* const* d_in, const int* in_sizes, int n_in,
                              void* d_out, int out_size, void* d_ws, size_t ws_size,
                              hipStream_t stream)
{
    const float* z      = (const float*)d_in[0];
    const int*   smask  = (const int*)d_in[1];
    const float* ln_g   = (const float*)d_in[2];
    const float* ln_b   = (const float*)d_in[3];
    const float* w_qkv  = (const float*)d_in[4];
    const float* w_pair = (const float*)d_in[5];
    const float* w_gate = (const float*)d_in[6];
    const float* b_gate = (const float*)d_in[7];
    const float* w_out  = (const float*)d_in[8];
    const float* b_out  = (const float*)d_in[9];
    float* out = (float*)d_out;

    short* ws      = (short*)d_ws;
    short* qkbT    = ws;                                   // 65536*256 (scrambled)
    short* Vtb     = qkbT + (size_t)NPOS * 256;            // 8388608 (phi)
    short* wT      = Vtb + (size_t)8388608;                // 528*128
    short* woT     = wT + 528 * 128;                       // 128*128
    unsigned* mjbg = (unsigned*)(woT + 128 * 128);         // 16 u32 (8 used)
    short* pbb     = (short*)(mjbg + 16);                  // 4*65536
    short* gate_b  = pbb + (size_t)4 * NPOS;               // 65536*128 ([p][c])
    short* aob     = gate_b + (size_t)NPOS * 128;          // 4*65536*32

    k_prep<<<64, 256, 0, stream>>>(w_qkv, w_gate, w_pair, w_out, smask, wT, woT, mjbg);
    k_proj<<<NPOS / 64, 256, 0, stream>>>(z, ln_g, ln_b, wT, b_gate, qkbT, Vtb, pbb, gate_b);
    k_attn<<<1024, 256, 0, stream>>>(qkbT, Vtb, pbb, smask, gate_b, mjbg, aob);
    k_out<<<NPOS / 64, 256, 0, stream>>>(aob, woT, b_out, out);
}

// Round 17
// 104.109 us; speedup vs baseline: 1.1335x; 1.0273x over previous
//
#include <hip/hip_runtime.h>
#include <hip/hip_bf16.h>
#include <math.h>

// TriangleAttention MI355X round 17 = R14 champion + 3 individually-validated tweaks:
//   (1) k_attn: mjc mask-word hoist (R16-validated), nothing else changed.
//   (2) k_out: XCD-local (r,qtr) decode matching k_attn -> aob reads L2-hit.
//   (3) k_proj pass B: cvt_pk uint2 packing for V/pb stores (R11-validated).
// B=1, N=256, IN_DIM=128, H=4, D=32.
//
// ws: qkbT short[65536*256] (scrambled), Vtb short[4*256*32*256] (phi),
//     wT short[528*128], woT short[128*128], mjbg u32[16],
//     pbb short[4*65536], gate_b short[65536*128] ([p][c]), aob short[4*65536*32]

#define NPOS 65536
#define LN_EPS 1e-5f
#define SCALE_L2E 0.25503487f        // (1/sqrt(32)) * log2(e)
#define MASKVAL  -1.4426950e-9f      // -1e-9 * log2(e)

typedef __attribute__((ext_vector_type(8))) short bf16x8;
typedef __attribute__((ext_vector_type(4))) float f32x4;

__device__ __forceinline__ short f2b(float f) {
    union { float f; unsigned u; } c; c.f = f;
    unsigned r = c.u + 0x7FFFu + ((c.u >> 16) & 1u);
    return (short)(r >> 16);
}
__device__ __forceinline__ unsigned cvt_pk(float lo, float hi) {
    unsigned r;
    asm("v_cvt_pk_bf16_f32 %0, %1, %2" : "=v"(r) : "v"(lo), "v"(hi));
    return r;
}
__device__ __forceinline__ float b2f_lo(unsigned u) {
    union { unsigned u; float f; } c; c.u = u << 16; return c.f;
}
__device__ __forceinline__ float b2f_hi(unsigned u) {
    union { unsigned u; float f; } c; c.u = u & 0xFFFF0000u; return c.f;
}

// ------------------------------------------------------------- weight prep
__global__ void k_prep(const float* __restrict__ wq, const float* __restrict__ wg,
                       const float* __restrict__ wp, const float* __restrict__ wo,
                       const int* __restrict__ smask,
                       short* __restrict__ wT, short* __restrict__ woT,
                       unsigned* __restrict__ mjbg)
{
    const int idx = blockIdx.x * 256 + threadIdx.x;
    const int stride = gridDim.x * 256;
    for (int i = idx; i < 528 * 128; i += stride) {
        const int o = i >> 7, c = i & 127;
        float v;
        if (o < 384)      v = wq[c * 384 + o];
        else if (o < 512) v = wg[c * 128 + (o - 384)];
        else if (o < 516) v = wp[c * 4 + (o - 512)] * 1.4426950408889634f;
        else              v = 0.f;
        wT[i] = f2b(v);
    }
    for (int i = idx; i < 128 * 128; i += stride) {
        const int o = i >> 7, c = i & 127;
        woT[i] = f2b(wo[c * 128 + o]);
    }
    if (blockIdx.x == 0 && threadIdx.x < 8) {
        const int gr = threadIdx.x >> 1, hw = threadIdx.x & 1;
        unsigned wbits = 0;
        for (int b = 0; b < 32; ++b) {
            const int k = hw * 32 + b;                    // k = nt*4 + reg
            const int j = (k >> 2) * 16 + gr * 4 + (k & 3);
            if (smask[j] == 0) wbits |= (1u << b);
        }
        mjbg[threadIdx.x] = wbits;
    }
}

// ------------------------------------------------------------- LN + projections
// 64 positions per block. qk stored direct-to-global (scrambled); 3 barriers.
__global__ __launch_bounds__(256, 4) void k_proj(
    const float* __restrict__ z, const float* __restrict__ ln_g,
    const float* __restrict__ ln_b, const short* __restrict__ wT,
    const float* __restrict__ b_gate, short* __restrict__ qkbT,
    short* __restrict__ Vtb, short* __restrict__ pbb, short* __restrict__ gate_b)
{
    __shared__ short sBuf[17920];   // sV [128][72] = 9216 | sZn/sG [64][136] = 8704
    const int t = threadIdx.x, w = t >> 6, l = t & 63;
    const int lg = l & 15, gr = l >> 4;
    const int p0 = blockIdx.x * 64;
    const f32x4 zero4 = {0.f, 0.f, 0.f, 0.f};
    short* sV = sBuf;            // [128][72]
    short* sZn = sBuf + 9216;    // [64][136]  (zn, later reused as gate stage)

    // --- LayerNorm: 4 threads per row, 32 channels each -> sZn [64][136]
    {
        const int row = t >> 2, q = t & 3;
        const float* zr = z + (size_t)(p0 + row) * 128 + q * 32;
        float v[32];
        float s = 0.f, sq = 0.f;
#pragma unroll
        for (int u = 0; u < 8; ++u) {
            const float4 f = ((const float4*)zr)[u];
            v[u * 4 + 0] = f.x; v[u * 4 + 1] = f.y;
            v[u * 4 + 2] = f.z; v[u * 4 + 3] = f.w;
            s += f.x + f.y + f.z + f.w;
            sq += f.x * f.x + f.y * f.y + f.z * f.z + f.w * f.w;
        }
        s  += __shfl_xor(s, 1, 4);  s  += __shfl_xor(s, 2, 4);
        sq += __shfl_xor(sq, 1, 4); sq += __shfl_xor(sq, 2, 4);
        const float mu = s * (1.f / 128.f);
        const float rstd = rsqrtf(sq * (1.f / 128.f) - mu * mu + LN_EPS);
        short tmp[32];
#pragma unroll
        for (int u = 0; u < 32; ++u) {
            const int c = q * 32 + u;
            tmp[u] = f2b((v[u] - mu) * rstd * ln_g[c] + ln_b[c]);
        }
        uint4* dst = (uint4*)(sZn + row * 136 + q * 32);
#pragma unroll
        for (int u = 0; u < 4; ++u) dst[u] = *(uint4*)&tmp[u * 8];
    }
    __syncthreads();   // barrier 1

    bf16x8 a[4][4];
#pragma unroll
    for (int mt = 0; mt < 4; ++mt)
#pragma unroll
        for (int kc = 0; kc < 4; ++kc)
            a[mt][kc] = *(const bf16x8*)(sZn + (mt * 16 + lg) * 136 + kc * 32 + gr * 8);
    __syncthreads();   // barrier 2 (zn region free for gate stage)

    // --- pass A: qk tiles nt 0..15 (SWAPPED), direct scrambled global stores
    short* qblk = qkbT + (size_t)blockIdx.x * 16384;
    for (int nt = w; nt < 16; nt += 4) {
        bf16x8 bfr[4];
#pragma unroll
        for (int kc = 0; kc < 4; ++kc)
            bfr[kc] = *(const bf16x8*)(wT + (size_t)(nt * 16 + lg) * 128 + kc * 32 + gr * 8);
#pragma unroll
        for (int mt = 0; mt < 4; ++mt) {
            f32x4 acc = zero4;
#pragma unroll
            for (int kc = 0; kc < 4; ++kc)
                acc = __builtin_amdgcn_mfma_f32_16x16x32_bf16(bfr[kc], a[mt][kc], acc, 0, 0, 0);
            uint2 pk;
            pk.x = cvt_pk(acc[0], acc[1]);
            pk.y = cvt_pk(acc[2], acc[3]);
            *(uint2*)(qblk + (nt * 4 + mt) * 256 + gr * 64 + lg * 4) = pk;
        }
    }

    // --- pass B: V (staged phi into sV, cvt_pk), gate (staged into sZn), pb direct (cvt_pk)
    for (int nt = 16 + w; nt < 33; nt += 4) {
        bf16x8 bfr[4];
#pragma unroll
        for (int kc = 0; kc < 4; ++kc)
            bfr[kc] = *(const bf16x8*)(wT + (size_t)(nt * 16 + lg) * 128 + kc * 32 + gr * 8);
        const int o = nt * 16 + lg;
#pragma unroll
        for (int mt = 0; mt < 4; ++mt) {
            f32x4 acc = zero4;
#pragma unroll
            for (int kc = 0; kc < 4; ++kc)
                acc = __builtin_amdgcn_mfma_f32_16x16x32_bf16(a[mt][kc], bfr[kc], acc, 0, 0, 0);
            const int pr = p0 + mt * 16 + gr * 4;
            if (o < 384) {
                const int row = o - 256;                    // hh*32 + d
                const int jl = mt * 16 + gr * 4;            // local j, 4-aligned
                const int jp = (jl & 0x23) | ((jl & 12) << 1) | ((jl >> 2) & 4);
                uint2 pk;
                pk.x = cvt_pk(acc[0], acc[1]);
                pk.y = cvt_pk(acc[2], acc[3]);
                *(uint2*)(sV + row * 72 + jp) = pk;
            } else if (o < 512) {
                const int c = o - 384;
                const float bg = b_gate[c];
#pragma unroll
                for (int reg = 0; reg < 4; ++reg)
                    sZn[(mt * 16 + gr * 4 + reg) * 136 + c] =
                        f2b(1.f / (1.f + __expf(-(acc[reg] + bg))));
            } else if (o < 516) {
                uint2 pk;
                pk.x = cvt_pk(acc[0], acc[1]);
                pk.y = cvt_pk(acc[2], acc[3]);
                *(uint2*)(pbb + (size_t)(o - 512) * NPOS + pr) = pk;
            }
        }
    }
    __syncthreads();   // barrier 3

    // --- coalesced write-out: V rows 64B/thread; gate rows 64B/thread
    {
        const int r = p0 >> 8, jbase = p0 & 255;
        const int row = t >> 1, half = t & 1;               // V: 128 rows x 2
        const short* src = sV + row * 72 + half * 32;
        const int hh = row >> 5, d = row & 31;
        short* dst = Vtb + (((size_t)hh * 256 + r) * 32 + d) * 256 + jbase + half * 32;
#pragma unroll
        for (int u = 0; u < 4; ++u)
            *(uint4*)(dst + u * 8) = *(const uint4*)(src + u * 8);

        const int grow = t >> 2, q = t & 3;                 // gate: 64 rows x 4
        const short* gsrc = sZn + grow * 136 + q * 32;
        short* gdst = gate_b + (size_t)(p0 + grow) * 128 + q * 32;
#pragma unroll
        for (int u = 0; u < 4; ++u)
            *(uint4*)(gdst + u * 8) = *(const uint4*)(gsrc + u * 8);
    }
}

// ------------------------------------------------------------- attention
// block = (r, h): grid 1024, XCD-local decode; 4 waves x 64 i.
// R14 body + hoisted mask word mjc (only change).
__global__ __launch_bounds__(256, 4) void k_attn(
    const short* __restrict__ qkbT, const short* __restrict__ Vtb,
    const short* __restrict__ pbb, const int* __restrict__ smask,
    const short* __restrict__ gate_b, const unsigned* __restrict__ mjbg,
    short* __restrict__ aob)
{
    __shared__ short sK[8192];   // [nt][gr][lg][8]  16KB, frag-packed
    __shared__ short sV[8192];   // [kcgr][d^(kcgr&7)][8]  16KB, XOR-swizzled
    const int t = threadIdx.x, wv = t >> 6, l = t & 63;
    const int lg = l & 15, gr = l >> 4;
    const int bid = blockIdx.x;
    const int r = (bid & 7) * 32 + (bid >> 5);   // XCD-local
    const int h = (bid >> 3) & 3;
    const int rb = r * 256;
    const f32x4 zero4 = {0.f, 0.f, 0.f, 0.f};
    const unsigned long long mjb = ((const unsigned long long*)mjbg)[gr];
    bf16x8 ones;
#pragma unroll
    for (int u = 0; u < 8; ++u) ones[u] = (short)0x3F80;

    // ---- stage K_h from scrambled qkbT
#pragma unroll
    for (int it = 0; it < 4; ++it) {
        const int chunk = it * 256 + t;
        const int j = chunk >> 2, dg = chunk & 3;
        const short* kb = qkbT + ((size_t)(r * 4 + (j >> 6))) * 16384
                        + ((8 + h * 2 + (dg >> 1)) * 4 + ((j >> 4) & 3)) * 256
                        + ((dg & 1) * 2) * 64 + (j & 15) * 4;
        uint4 v;
        { const uint2 lo = *(const uint2*)kb, hi = *(const uint2*)(kb + 64);
          v.x = lo.x; v.y = lo.y; v.z = hi.x; v.w = hi.y; }
        *(uint4*)(sK + (((j >> 4) * 4 + dg) * 16 + (j & 15)) * 8) = v;
    }
    // ---- stage V_h: contiguous 4KB per iteration (phi layout in Vtb)
#pragma unroll
    for (int it = 0; it < 4; ++it) {
        const int d = it * 8 + (t >> 5), kcgr = t & 31;
        const uint4 v = *(const uint4*)(Vtb + (((size_t)h * 256 + r) * 32 + d) * 256 + kcgr * 8);
        *(uint4*)(sV + (kcgr * 32 + (d ^ (kcgr & 7))) * 8) = v;
    }
    __syncthreads();

    for (int tl = 0; tl < 4; ++tl) {
        const int i0 = wv * 64 + tl * 16;
        // Q frag from scrambled qkbT
        bf16x8 qf;
        {
            const short* qb = qkbT + ((size_t)(r * 4 + wv)) * 16384
                            + ((h * 2 + (gr >> 1)) * 4 + tl) * 256
                            + ((gr & 1) * 2) * 64 + lg * 4;
            union { bf16x8 v; uint2 u2[2]; } qu;
            qu.u2[0] = *(const uint2*)qb;
            qu.u2[1] = *(const uint2*)(qb + 64);
            qf = qu.v;
        }
        const bool bi = smask[i0 + lg] == 0;
        const unsigned long long mjc = bi ? ~mjb : mjb;   // hoisted mask word
        const short* pbrow = pbb + (size_t)h * NPOS + (size_t)(i0 + lg) * 256;

        f32x4 o0 = zero4, o1 = zero4, o2 = zero4;

        // ---- half A: softmax nt 0..7 -> pkA, then PV kc 0..3
        unsigned pkA[16];
#pragma unroll
        for (int nt = 0; nt < 8; ++nt) {
            const bf16x8 kf = *(const bf16x8*)(sK + ((nt * 4 + gr) * 16 + lg) * 8);
            const uint2 pbp = *(const uint2*)(pbrow + nt * 16 + gr * 4);
            const f32x4 s4 = __builtin_amdgcn_mfma_f32_16x16x32_bf16(kf, qf, zero4, 0, 0, 0);
            const float pbv[4] = { b2f_lo(pbp.x), b2f_hi(pbp.x), b2f_lo(pbp.y), b2f_hi(pbp.y) };
            float pv[4];
#pragma unroll
            for (int reg = 0; reg < 4; ++reg) {
                float lv = fmaf(s4[reg], SCALE_L2E, pbv[reg]);
                lv = ((mjc >> (nt * 4 + reg)) & 1) ? MASKVAL : lv;
                pv[reg] = exp2f(lv);
            }
            pkA[nt * 2 + 0] = cvt_pk(pv[0], pv[1]);
            pkA[nt * 2 + 1] = cvt_pk(pv[2], pv[3]);
        }
        __builtin_amdgcn_s_setprio(1);
#pragma unroll
        for (int kc = 0; kc < 4; ++kc) {
            const int kcgr = kc * 4 + gr, c7 = kcgr & 7;
            const bf16x8 pa = *(const bf16x8*)(&pkA[kc * 4]);
            const bf16x8 v0 = *(const bf16x8*)(sV + (kcgr * 32 + (lg ^ c7)) * 8);
            const bf16x8 v1 = *(const bf16x8*)(sV + (kcgr * 32 + 16 + (lg ^ c7)) * 8);
            o0 = __builtin_amdgcn_mfma_f32_16x16x32_bf16(pa, v0, o0, 0, 0, 0);
            o1 = __builtin_amdgcn_mfma_f32_16x16x32_bf16(pa, v1, o1, 0, 0, 0);
            o2 = __builtin_amdgcn_mfma_f32_16x16x32_bf16(pa, ones, o2, 0, 0, 0);
        }
        __builtin_amdgcn_s_setprio(0);

        // ---- half B: softmax nt 8..15, then PV kc 4..7
        unsigned pkB[16];
#pragma unroll
        for (int nt = 8; nt < 16; ++nt) {
            const bf16x8 kf = *(const bf16x8*)(sK + ((nt * 4 + gr) * 16 + lg) * 8);
            const uint2 pbp = *(const uint2*)(pbrow + nt * 16 + gr * 4);
            const f32x4 s4 = __builtin_amdgcn_mfma_f32_16x16x32_bf16(kf, qf, zero4, 0, 0, 0);
            const float pbv[4] = { b2f_lo(pbp.x), b2f_hi(pbp.x), b2f_lo(pbp.y), b2f_hi(pbp.y) };
            float pv[4];
#pragma unroll
            for (int reg = 0; reg < 4; ++reg) {
                float lv = fmaf(s4[reg], SCALE_L2E, pbv[reg]);
                lv = ((mjc >> (nt * 4 + reg)) & 1) ? MASKVAL : lv;
                pv[reg] = exp2f(lv);
            }
            pkB[(nt - 8) * 2 + 0] = cvt_pk(pv[0], pv[1]);
            pkB[(nt - 8) * 2 + 1] = cvt_pk(pv[2], pv[3]);
        }
        __builtin_amdgcn_s_setprio(1);
#pragma unroll
        for (int kc = 4; kc < 8; ++kc) {
            const int kcgr = kc * 4 + gr, c7 = kcgr & 7;
            const bf16x8 pa = *(const bf16x8*)(&pkB[(kc - 4) * 4]);
            const bf16x8 v0 = *(const bf16x8*)(sV + (kcgr * 32 + (lg ^ c7)) * 8);
            const bf16x8 v1 = *(const bf16x8*)(sV + (kcgr * 32 + 16 + (lg ^ c7)) * 8);
            o0 = __builtin_amdgcn_mfma_f32_16x16x32_bf16(pa, v0, o0, 0, 0, 0);
            o1 = __builtin_amdgcn_mfma_f32_16x16x32_bf16(pa, v1, o1, 0, 0, 0);
            o2 = __builtin_amdgcn_mfma_f32_16x16x32_bf16(pa, ones, o2, 0, 0, 0);
        }
        __builtin_amdgcn_s_setprio(0);

        // ---- epilogue: normalize, gate, write aob[h][p][d] (bf16)
#pragma unroll
        for (int reg = 0; reg < 4; ++reg) {
            const int p = rb + i0 + gr * 4 + reg;
            const float g0 = b2f_lo((unsigned)*(const unsigned short*)(gate_b + (size_t)p * 128 + h * 32 + lg));
            const float g1 = b2f_lo((unsigned)*(const unsigned short*)(gate_b + (size_t)p * 128 + h * 32 + 16 + lg));
            const float inv = 1.f / o2[reg];
            short* dst = aob + ((size_t)h * NPOS + p) * 32;
            dst[lg]      = f2b(o0[reg] * inv * g0);
            dst[16 + lg] = f2b(o1[reg] * inv * g1);
        }
    }
}

// ------------------------------------------------------------- out projection
// XCD-local decode matching k_attn: aob rows for r are L2-resident on this XCD.
__global__ __launch_bounds__(256) void k_out(
    const short* __restrict__ aob, const short* __restrict__ woT,
    const float* __restrict__ b_out, float* __restrict__ out)
{
    const int t = threadIdx.x, w = t >> 6, l = t & 63;
    const int lg = l & 15, gr = l >> 4;
    const int bid = blockIdx.x;
    const int r = (bid & 7) * 32 + (bid >> 5);   // same decode as k_attn
    const int qtr = (bid >> 3) & 3;
    const int p0 = r * 256 + qtr * 64;
    const f32x4 zero4 = {0.f, 0.f, 0.f, 0.f};

    bf16x8 a[4][4];   // [mt][kc]; kc = head
#pragma unroll
    for (int mt = 0; mt < 4; ++mt)
#pragma unroll
        for (int kc = 0; kc < 4; ++kc)
            a[mt][kc] = *(const bf16x8*)(aob + ((size_t)kc * NPOS + p0 + mt * 16 + lg) * 32 + gr * 8);

    for (int nt = w; nt < 8; nt += 4) {
        bf16x8 bw[4];
#pragma unroll
        for (int kc = 0; kc < 4; ++kc)
            bw[kc] = *(const bf16x8*)(woT + (size_t)(nt * 16 + lg) * 128 + kc * 32 + gr * 8);
        const int o = nt * 16 + lg;
        const float bo = b_out[o];
#pragma unroll
        for (int mt = 0; mt < 4; ++mt) {
            f32x4 c = zero4;
#pragma unroll
            for (int kc = 0; kc < 4; ++kc)
                c = __builtin_amdgcn_mfma_f32_16x16x32_bf16(a[mt][kc], bw[kc], c, 0, 0, 0);
#pragma unroll
            for (int reg = 0; reg < 4; ++reg)
                out[(size_t)(p0 + mt * 16 + gr * 4 + reg) * 128 + o] = c[reg] + bo;
        }
    }
}

// ------------------------------------------------------------- launch
extern "C" void kernel_launch(void* const* d_in, const int* in_sizes, int n_in,
                              void* d_out, int out_size, void* d_ws, size_t ws_size,
                              hipStream_t stream)
{
    const float* z      = (const float*)d_in[0];
    const int*   smask  = (const int*)d_in[1];
    const float* ln_g   = (const float*)d_in[2];
    const float* ln_b   = (const float*)d_in[3];
    const float* w_qkv  = (const float*)d_in[4];
    const float* w_pair = (const float*)d_in[5];
    const float* w_gate = (const float*)d_in[6];
    const float* b_gate = (const float*)d_in[7];
    const float* w_out  = (const float*)d_in[8];
    const float* b_out  = (const float*)d_in[9];
    float* out = (float*)d_out;

    short* ws      = (short*)d_ws;
    short* qkbT    = ws;                                   // 65536*256 (scrambled)
    short* Vtb     = qkbT + (size_t)NPOS * 256;            // 8388608 (phi)
    short* wT      = Vtb + (size_t)8388608;                // 528*128
    short* woT     = wT + 528 * 128;                       // 128*128
    unsigned* mjbg = (unsigned*)(woT + 128 * 128);         // 16 u32 (8 used)
    short* pbb     = (short*)(mjbg + 16);                  // 4*65536
    short* gate_b  = pbb + (size_t)4 * NPOS;               // 65536*128 ([p][c])
    short* aob     = gate_b + (size_t)NPOS * 128;          // 4*65536*32

    k_prep<<<64, 256, 0, stream>>>(w_qkv, w_gate, w_pair, w_out, smask, wT, woT, mjbg);
    k_proj<<<NPOS / 64, 256, 0, stream>>>(z, ln_g, ln_b, wT, b_gate, qkbT, Vtb, pbb, gate_b);
    k_attn<<<1024, 256, 0, stream>>>(qkbT, Vtb, pbb, smask, gate_b, mjbg, aob);
    k_out<<<NPOS / 64, 256, 0, stream>>>(aob, woT, b_out, out);
}